// Round 1
// baseline (270.543 us; speedup 1.0000x reference)
//
#include <hip/hip_runtime.h>

// FastVolterra1: out[r,:] = irfft(rfft(x[r,:]) * softmax(w1)), D=1024.
// Implemented as radix-4 Stockham FFT (fwd) -> gate mult -> radix-4 Stockham
// inverse FFT, one row per 256-thread block, data in LDS (re/im split arrays).
// Stockham property: reads are always cur[t + 256*k]; writes reorder.

#define D_N 1024
#define TWO_PI_OVER_N 6.1359231515426636e-03f  // 2*pi/1024

__device__ __forceinline__ void cmulf(float& xr, float& xi, float wr, float wi) {
    float r = xr * wr - xi * wi;
    float i = xr * wi + xi * wr;
    xr = r; xi = i;
}

// One radix-4 Stockham stage: butterfly on 4 complex inputs (already loaded by
// caller from cur[t+256k]), twiddle, store to yr/yi at q + S*(4p+k).
// Forward DFT uses e^{-i}; INV conjugates all constants.
template <int S, bool INV>
__device__ __forceinline__ void fft_stage_store(
    int t,
    float ar, float ai, float br, float bi,
    float cr, float ci, float dr, float di,
    float* __restrict__ yr, float* __restrict__ yi)
{
    float apcr = ar + cr, apci = ai + ci;
    float amcr = ar - cr, amci = ai - ci;
    float bpdr = br + dr, bpdi = bi + di;
    float bmdr = br - dr, bmdi = bi - di;

    float y0r = apcr + bpdr, y0i = apci + bpdi;
    float y2r = apcr - bpdr, y2i = apci - bpdi;
    float y1r, y1i, y3r, y3i;
    if (!INV) {
        // y1 = amc - j*bmd ; y3 = amc + j*bmd   (j*z = (-zi, zr))
        y1r = amcr + bmdi; y1i = amci - bmdr;
        y3r = amcr - bmdi; y3i = amci + bmdr;
    } else {
        y1r = amcr - bmdi; y1i = amci + bmdr;
        y3r = amcr + bmdi; y3i = amci - bmdr;
    }

    if (S < 256) {  // S==256 => p==0 => twiddles are 1
        int j = t & ~(S - 1);  // j = S*p, twiddle = exp(-+ 2*pi*i*j/1024)
        float ang = (float)j * TWO_PI_OVER_N;
        float sn, cs;
        __sincosf(ang, &sn, &cs);
        float w1r = cs, w1i = INV ? sn : -sn;
        float w2r = w1r * w1r - w1i * w1i, w2i = 2.0f * w1r * w1i;
        float w3r = w2r * w1r - w2i * w1i, w3i = w2r * w1i + w2i * w1r;
        cmulf(y1r, y1i, w1r, w1i);
        cmulf(y2r, y2i, w2r, w2i);
        cmulf(y3r, y3i, w3r, w3i);
    }

    int bw = (t & (S - 1)) + ((t & ~(S - 1)) << 2);  // q + 4*S*p
    yr[bw        ] = y0r; yi[bw        ] = y0i;
    yr[bw +     S] = y1r; yi[bw +     S] = y1i;
    yr[bw + 2 * S] = y2r; yi[bw + 2 * S] = y2i;
    yr[bw + 3 * S] = y3r; yi[bw + 3 * S] = y3i;
}

__global__ __launch_bounds__(256)
void fft_filter_kernel(const float* __restrict__ x,
                       const float* __restrict__ G,   // gate[min(f,1024-f)]/1024
                       float* __restrict__ out)
{
    __shared__ float lAr[D_N], lAi[D_N], lBr[D_N], lBi[D_N];
    const int t = threadIdx.x;
    const size_t base = (size_t)blockIdx.x * D_N;

    // ---- forward FFT (5 radix-4 Stockham stages), e^{-i} kernel ----
    // stage s=1: read global (imag = 0), write B
    {
        float x0 = x[base + t];
        float x1 = x[base + t + 256];
        float x2 = x[base + t + 512];
        float x3 = x[base + t + 768];
        fft_stage_store<1, false>(t, x0, 0.f, x1, 0.f, x2, 0.f, x3, 0.f, lBr, lBi);
    }
    __syncthreads();
    fft_stage_store<4, false>(t,
        lBr[t], lBi[t], lBr[t + 256], lBi[t + 256],
        lBr[t + 512], lBi[t + 512], lBr[t + 768], lBi[t + 768], lAr, lAi);
    __syncthreads();
    fft_stage_store<16, false>(t,
        lAr[t], lAi[t], lAr[t + 256], lAi[t + 256],
        lAr[t + 512], lAi[t + 512], lAr[t + 768], lAi[t + 768], lBr, lBi);
    __syncthreads();
    fft_stage_store<64, false>(t,
        lBr[t], lBi[t], lBr[t + 256], lBi[t + 256],
        lBr[t + 512], lBi[t + 512], lBr[t + 768], lBi[t + 768], lAr, lAi);
    __syncthreads();
    fft_stage_store<256, false>(t,
        lAr[t], lAi[t], lAr[t + 256], lAi[t + 256],
        lAr[t + 512], lAi[t + 512], lAr[t + 768], lAi[t + 768], lBr, lBi);
    __syncthreads();
    // B now holds X[f] in natural order.

    // ---- gate (fused into first inverse-stage reads) + inverse FFT ----
    {
        float g0 = G[t], g1 = G[t + 256], g2 = G[t + 512], g3 = G[t + 768];
        fft_stage_store<1, true>(t,
            lBr[t] * g0, lBi[t] * g0,
            lBr[t + 256] * g1, lBi[t + 256] * g1,
            lBr[t + 512] * g2, lBi[t + 512] * g2,
            lBr[t + 768] * g3, lBi[t + 768] * g3, lAr, lAi);
    }
    __syncthreads();
    fft_stage_store<4, true>(t,
        lAr[t], lAi[t], lAr[t + 256], lAi[t + 256],
        lAr[t + 512], lAi[t + 512], lAr[t + 768], lAi[t + 768], lBr, lBi);
    __syncthreads();
    fft_stage_store<16, true>(t,
        lBr[t], lBi[t], lBr[t + 256], lBi[t + 256],
        lBr[t + 512], lBi[t + 512], lBr[t + 768], lBi[t + 768], lAr, lAi);
    __syncthreads();
    fft_stage_store<64, true>(t,
        lAr[t], lAi[t], lAr[t + 256], lAi[t + 256],
        lAr[t + 512], lAi[t + 512], lAr[t + 768], lAi[t + 768], lBr, lBi);
    __syncthreads();
    // last inverse stage s=256: twiddles = 1, write real part to global
    {
        float ar = lBr[t],       ai = lBi[t];
        float br = lBr[t + 256], bi = lBi[t + 256];
        float cr = lBr[t + 512], ci = lBi[t + 512];
        float dr = lBr[t + 768], di = lBi[t + 768];
        float apcr = ar + cr, amcr = ar - cr;
        float bpdr = br + dr, bmdi = bi - di;
        (void)ai; (void)ci;
        float y0r = apcr + bpdr;
        float y2r = apcr - bpdr;
        float y1r = amcr - bmdi;  // INV: y1 = amc - j*bmd (real part)
        float y3r = amcr + bmdi;
        out[base + t      ] = y0r;
        out[base + t + 256] = y1r;
        out[base + t + 512] = y2r;
        out[base + t + 768] = y3r;
    }
}

// Compute G[f] = softmax(w1)[min(f, 1024-f)] / 1024 for f in [0,1024).
__global__ void gate_kernel(const float* __restrict__ w1, float* __restrict__ G)
{
    __shared__ float red[1024];
    __shared__ float ex[513];
    const int t = threadIdx.x;  // 1024 threads

    float v = (t < 513) ? w1[t] : -1e30f;
    red[t] = v;
    __syncthreads();
    for (int off = 512; off > 0; off >>= 1) {
        if (t < off) red[t] = fmaxf(red[t], red[t + off]);
        __syncthreads();
    }
    float M = red[0];
    __syncthreads();

    float e = (t < 513) ? expf(w1[t] - M) : 0.0f;
    if (t < 513) ex[t] = e;
    red[t] = e;
    __syncthreads();
    for (int off = 512; off > 0; off >>= 1) {
        if (t < off) red[t] += red[t + off];
        __syncthreads();
    }
    float inv = 1.0f / (red[0] * 1024.0f);

    int k = (t <= 512) ? t : (1024 - t);
    G[t] = ex[k] * inv;
}

extern "C" void kernel_launch(void* const* d_in, const int* in_sizes, int n_in,
                              void* d_out, int out_size, void* d_ws, size_t ws_size,
                              hipStream_t stream)
{
    const float* hidden = (const float*)d_in[0];   // [B*L, 1024] fp32
    const float* w1     = (const float*)d_in[1];   // [513] fp32
    float* out = (float*)d_out;
    float* G   = (float*)d_ws;                      // 1024 floats scratch

    gate_kernel<<<1, 1024, 0, stream>>>(w1, G);

    const int rows = in_sizes[0] / D_N;            // 32768
    fft_filter_kernel<<<rows, 256, 0, stream>>>(hidden, G, out);
}

// Round 2
// 236.141 us; speedup vs baseline: 1.1457x; 1.1457x over previous
//
#include <hip/hip_runtime.h>

// FastVolterra1: out[r,:] = irfft(rfft(x[r,:]) * softmax(w1)), D=1024, fp32.
//
// Real-packed formulation: z[n] = x[2n] + i*x[2n+1] (length 512).
//   Z = FFT_512(z)
//   W[k] = P[k]*Z[k] + i*q[k]*conj(Z[(512-k)%512])   (P,q real, precomputed
//          from gate + pack/unpack twiddles, 1/512 IFFT norm folded in)
//   w = IFFT_512(W);  out[2n] = Re w[n], out[2n+1] = Im w[n].
//
// FFT-512 = 3 radix-8 Stockham stages (S = 1, 8, 64), 64 threads per row,
// 4 rows (= 4 waves) per 256-thread block. One row == one wave, so NO
// __syncthreads() is needed: same-wave LDS ops execute in order.
// Twiddles come from tables precomputed in d_ws (inverse = conjugate, via
// compile-time flag). LDS element indices pass through an XOR swizzle that
// makes every stage's read/write pattern <=2 lanes/bank (conflict-free).

__device__ __forceinline__ int sw(int a) {
    return a ^ (int)((((unsigned)a >> 6) * 9u) & 31u);
}

// 8-point DFT, bins in order. Forward = e^{-2pi i/8} kernel; INV conjugates.
template <bool INV>
__device__ __forceinline__ void bfly8(float* xr, float* xi)
{
    const float r2 = 0.70710678118654752f;
    // even DFT4 on (x0,x2,x4,x6)
    float t0r = xr[0] + xr[4], t0i = xi[0] + xi[4];
    float t1r = xr[0] - xr[4], t1i = xi[0] - xi[4];
    float t2r = xr[2] + xr[6], t2i = xi[2] + xi[6];
    float t3r = xr[2] - xr[6], t3i = xi[2] - xi[6];
    float e0r = t0r + t2r, e0i = t0i + t2i;
    float e2r = t0r - t2r, e2i = t0i - t2i;
    float e1r, e1i, e3r, e3i;
    if (!INV) { e1r = t1r + t3i; e1i = t1i - t3r; e3r = t1r - t3i; e3i = t1i + t3r; }
    else      { e1r = t1r - t3i; e1i = t1i + t3r; e3r = t1r + t3i; e3i = t1i - t3r; }
    // odd DFT4 on (x1,x3,x5,x7)
    float s0r = xr[1] + xr[5], s0i = xi[1] + xi[5];
    float s1r = xr[1] - xr[5], s1i = xi[1] - xi[5];
    float s2r = xr[3] + xr[7], s2i = xi[3] + xi[7];
    float s3r = xr[3] - xr[7], s3i = xi[3] - xi[7];
    float o0r = s0r + s2r, o0i = s0i + s2i;
    float o2r = s0r - s2r, o2i = s0i - s2i;
    float o1r, o1i, o3r, o3i;
    if (!INV) { o1r = s1r + s3i; o1i = s1i - s3r; o3r = s1r - s3i; o3i = s1i + s3r; }
    else      { o1r = s1r - s3i; o1i = s1i + s3r; o3r = s1r + s3i; o3i = s1i - s3r; }
    // multiply odd bins by w8^k
    float p1r, p1i, p2r, p2i, p3r, p3i;
    if (!INV) {
        p1r = (o1r + o1i) * r2;  p1i = (o1i - o1r) * r2;   // *(1-i)/sqrt2
        p2r = o2i;               p2i = -o2r;               // *(-i)
        p3r = (o3i - o3r) * r2;  p3i = -(o3r + o3i) * r2;  // *(-1-i)/sqrt2
    } else {
        p1r = (o1r - o1i) * r2;  p1i = (o1i + o1r) * r2;   // *(1+i)/sqrt2
        p2r = -o2i;              p2i = o2r;                // *(+i)
        p3r = -(o3r + o3i) * r2; p3i = (o3r - o3i) * r2;   // *(-1+i)/sqrt2
    }
    xr[0] = e0r + o0r; xi[0] = e0i + o0i;
    xr[4] = e0r - o0r; xi[4] = e0i - o0i;
    xr[1] = e1r + p1r; xi[1] = e1i + p1i;
    xr[5] = e1r - p1r; xi[5] = e1i - p1i;
    xr[2] = e2r + p2r; xi[2] = e2i + p2i;
    xr[6] = e2r - p2r; xi[6] = e2i - p2i;
    xr[3] = e3r + p3r; xi[3] = e3i + p3i;
    xr[7] = e3r - p3r; xi[7] = e3i - p3i;
}

// Tables store (cos th, sin th), th >= 0. Forward multiplies by e^{-i th}.
template <bool INV>
__device__ __forceinline__ void tw_apply(float* xr, float* xi,
                                         const float* c, const float* s)
{
#pragma unroll
    for (int k = 1; k < 8; ++k) {
        float r, i;
        if (!INV) { r = xr[k] * c[k] + xi[k] * s[k]; i = xi[k] * c[k] - xr[k] * s[k]; }
        else      { r = xr[k] * c[k] - xi[k] * s[k]; i = xi[k] * c[k] + xr[k] * s[k]; }
        xr[k] = r; xi[k] = i;
    }
}

template <int S>
__device__ __forceinline__ void store_stage(int t, const float* xr, const float* xi,
                                            float* dr, float* di)
{
    int base = (t & (S - 1)) + ((t & ~(S - 1)) << 3);
#pragma unroll
    for (int k = 0; k < 8; ++k) {
        int idx = sw(base + k * S);
        dr[idx] = xr[k]; di[idx] = xi[k];
    }
}

__device__ __forceinline__ void load_stage(int t, float* xr, float* xi,
                                           const float* dr, const float* di)
{
#pragma unroll
    for (int k = 0; k < 8; ++k) {
        int idx = sw(t + 64 * k);
        xr[k] = dr[idx]; xi[k] = di[idx];
    }
}

__global__ __launch_bounds__(256)
void fv_kernel(const float2* __restrict__ x,
               const float2* __restrict__ pq,    // (P[k], q[k]) k=0..511
               const float2* __restrict__ tw1,   // [(k-1)*64 + t], k=1..7
               const float2* __restrict__ tw8,   // [(k-1)*8 + p],  k=1..7
               float2* __restrict__ out)
{
    __shared__ float Ar[4][512], Ai[4][512], Br[4][512], Bi[4][512];
    const int tid = threadIdx.x;
    const int r = tid >> 6;      // row within block == wave id
    const int t = tid & 63;      // lane
    float* ar = Ar[r]; float* ai = Ai[r];
    float* br = Br[r]; float* bi = Bi[r];
    const size_t rowbase = ((size_t)blockIdx.x * 4 + r) * 512;  // float2 units

    // twiddle register sets
    float c1[8], s1[8], c8[8], s8[8];
#pragma unroll
    for (int k = 1; k < 8; ++k) {
        float2 w = tw1[(k - 1) * 64 + t];        c1[k] = w.x; s1[k] = w.y;
        float2 v = tw8[(k - 1) * 8 + (t >> 3)];  c8[k] = v.x; s8[k] = v.y;
    }

    float zr[8], zi[8];

    // ---- forward FFT-512 ----
#pragma unroll
    for (int k = 0; k < 8; ++k) {
        float2 v = x[rowbase + t + 64 * k];
        zr[k] = v.x; zi[k] = v.y;
    }
    bfly8<false>(zr, zi);
    tw_apply<false>(zr, zi, c1, s1);
    store_stage<1>(t, zr, zi, ar, ai);

    load_stage(t, zr, zi, ar, ai);
    bfly8<false>(zr, zi);
    tw_apply<false>(zr, zi, c8, s8);
    store_stage<8>(t, zr, zi, br, bi);

    load_stage(t, zr, zi, br, bi);
    bfly8<false>(zr, zi);
    store_stage<64>(t, zr, zi, ar, ai);   // Z natural order in a

    // ---- combine W[k] = P*Z[k] + i*q*conj(Z[512-k]) fused into inv stage 1 ----
#pragma unroll
    for (int k = 0; k < 8; ++k) {
        int idx = t + 64 * k;
        int mir = (512 - idx) & 511;
        float ur = ar[sw(idx)], ui = ai[sw(idx)];
        float vr = ar[sw(mir)], vi = ai[sw(mir)];
        float2 g = pq[idx];
        zr[k] = g.x * ur + g.y * vi;
        zi[k] = g.x * ui + g.y * vr;
    }
    bfly8<true>(zr, zi);
    tw_apply<true>(zr, zi, c1, s1);
    store_stage<1>(t, zr, zi, br, bi);

    load_stage(t, zr, zi, br, bi);
    bfly8<true>(zr, zi);
    tw_apply<true>(zr, zi, c8, s8);
    store_stage<8>(t, zr, zi, ar, ai);

    load_stage(t, zr, zi, ar, ai);
    bfly8<true>(zr, zi);
#pragma unroll
    for (int k = 0; k < 8; ++k) {
        out[rowbase + t + 64 * k] = make_float2(zr[k], zi[k]);
    }
}

// Build softmax gate, then P/q table and twiddle tables, all in d_ws.
__global__ void gate_kernel(const float* __restrict__ w1,
                            float2* __restrict__ pq,
                            float2* __restrict__ tw1,
                            float2* __restrict__ tw8)
{
    __shared__ float red[1024];
    __shared__ float ex[513];
    const int t = threadIdx.x;  // 1024 threads

    float v = (t < 513) ? w1[t] : -1e30f;
    red[t] = v;
    __syncthreads();
    for (int off = 512; off > 0; off >>= 1) {
        if (t < off) red[t] = fmaxf(red[t], red[t + off]);
        __syncthreads();
    }
    float M = red[0];
    __syncthreads();

    float e = (t < 513) ? expf(w1[t] - M) : 0.0f;
    if (t < 513) ex[t] = e;
    red[t] = e;
    __syncthreads();
    for (int off = 512; off > 0; off >>= 1) {
        if (t < off) red[t] += red[t + off];
        __syncthreads();
    }
    float inv = 1.0f / red[0];
    __syncthreads();

    if (t < 512) {
        float ga = ex[t] * inv;
        float gb = ex[512 - t] * inv;
        float gp = ga + gb, gm = ga - gb;
        float th = (float)t * 3.06796157577128245e-03f;  // pi/1024 * 2 * t/2... = 2*pi*t/2048*2 -> pi*t/512? see below
        // theta = 2*pi*t/1024 = pi*t/512 = t * 6.13592315e-3? No:
        // pi/512 = 6.135923151542565e-03
        th = (float)t * 6.13592315154256492e-03f;
        float sn, cs;
        __sincosf(th, &sn, &cs);
        float P = 0.5f * (gp - gm * sn) * (1.0f / 512.0f);
        float q = 0.5f * (gm * cs) * (1.0f / 512.0f);
        pq[t] = make_float2(P, q);
    }
    if (t < 448) {
        int k = (t >> 6) + 1;
        int j = t & 63;
        // theta = 2*pi*j*k/512
        float th = (float)(j * k) * 1.22718463151036952e-02f;  // 2*pi/512
        float sn, cs;
        sincosf(th, &sn, &cs);
        tw1[t] = make_float2(cs, sn);
    }
    if (t < 56) {
        int k = (t >> 3) + 1;
        int p = t & 7;
        // theta = 2*pi*p*k/64
        float th = (float)(p * k) * 9.81747704246810387e-02f;  // 2*pi/64
        float sn, cs;
        sincosf(th, &sn, &cs);
        tw8[t] = make_float2(cs, sn);
    }
}

extern "C" void kernel_launch(void* const* d_in, const int* in_sizes, int n_in,
                              void* d_out, int out_size, void* d_ws, size_t ws_size,
                              hipStream_t stream)
{
    (void)n_in; (void)out_size; (void)ws_size;
    const float2* hidden = (const float2*)d_in[0];   // [32768 rows, 512 float2]
    const float*  w1     = (const float*)d_in[1];    // [513]
    float2* out = (float2*)d_out;

    float2* pq  = (float2*)d_ws;          // 512 float2
    float2* tw1 = pq + 512;               // 448 float2
    float2* tw8 = tw1 + 448;              // 56  float2

    gate_kernel<<<1, 1024, 0, stream>>>(w1, pq, tw1, tw8);

    const int rows   = in_sizes[0] / 1024;   // 32768
    const int blocks = rows / 4;             // 8192
    fv_kernel<<<blocks, 256, 0, stream>>>(hidden, pq, tw1, tw8, out);
}

// Round 3
// 234.707 us; speedup vs baseline: 1.1527x; 1.0061x over previous
//
#include <hip/hip_runtime.h>

// FastVolterra1: out[r,:] = irfft(rfft(x[r,:]) * softmax(w1)), D=1024, fp32.
//
// Real-packed: z[n] = x[2n] + i*x[2n+1] (length 512);
//   Z = FFT_512(z);  W[k] = P[k]*Z[k] + i*q[k]*conj(Z[(512-k)%512]);
//   w = IFFT_512(W); out[2n]=Re w[n], out[2n+1]=Im w[n].
// P,q real, precomputed from softmax gate (1/512 norm folded in).
//
// FFT-512 = 3 radix-8 Stockham stages. 64 threads/row, 4 rows (=4 waves) per
// block; one row == one wave -> NO __syncthreads (same-wave LDS ops are
// in-order; empirically verified by round-2 kernel passing barrier-free).
// LDS uses pad(e)=e+(e>>4) (544-float rows): every stage's access pattern
// touches each bank exactly 2x per wave-op = conflict-free (m136: 2-way free).
// The fwd-stage3 -> combine -> inv-stage1 transition needs no LDS at all:
// Z sits in regs in natural (t+64k) layout; the conjugate-mirror partner is
// lane (64-t)&63 reg 7-k, fetched with __shfl (lane 0 self-pairs).

#define R2F 0.70710678118654752f

// 8-point DFT, bins in natural order. Forward = e^{-2pi i/8}; INV conjugates.
template <bool INV>
__device__ __forceinline__ void bfly8(float* xr, float* xi)
{
    float t0r = xr[0] + xr[4], t0i = xi[0] + xi[4];
    float t1r = xr[0] - xr[4], t1i = xi[0] - xi[4];
    float t2r = xr[2] + xr[6], t2i = xi[2] + xi[6];
    float t3r = xr[2] - xr[6], t3i = xi[2] - xi[6];
    float e0r = t0r + t2r, e0i = t0i + t2i;
    float e2r = t0r - t2r, e2i = t0i - t2i;
    float e1r, e1i, e3r, e3i;
    if (!INV) { e1r = t1r + t3i; e1i = t1i - t3r; e3r = t1r - t3i; e3i = t1i + t3r; }
    else      { e1r = t1r - t3i; e1i = t1i + t3r; e3r = t1r + t3i; e3i = t1i - t3r; }
    float s0r = xr[1] + xr[5], s0i = xi[1] + xi[5];
    float s1r = xr[1] - xr[5], s1i = xi[1] - xi[5];
    float s2r = xr[3] + xr[7], s2i = xi[3] + xi[7];
    float s3r = xr[3] - xr[7], s3i = xi[3] - xi[7];
    float o0r = s0r + s2r, o0i = s0i + s2i;
    float o2r = s0r - s2r, o2i = s0i - s2i;
    float o1r, o1i, o3r, o3i;
    if (!INV) { o1r = s1r + s3i; o1i = s1i - s3r; o3r = s1r - s3i; o3i = s1i + s3r; }
    else      { o1r = s1r - s3i; o1i = s1i + s3r; o3r = s1r + s3i; o3i = s1i - s3r; }
    float p1r, p1i, p2r, p2i, p3r, p3i;
    if (!INV) {
        p1r = (o1r + o1i) * R2F;  p1i = (o1i - o1r) * R2F;
        p2r = o2i;                p2i = -o2r;
        p3r = (o3i - o3r) * R2F;  p3i = -(o3r + o3i) * R2F;
    } else {
        p1r = (o1r - o1i) * R2F;  p1i = (o1i + o1r) * R2F;
        p2r = -o2i;               p2i = o2r;
        p3r = -(o3r + o3i) * R2F; p3i = (o3r - o3i) * R2F;
    }
    xr[0] = e0r + o0r; xi[0] = e0i + o0i;
    xr[4] = e0r - o0r; xi[4] = e0i - o0i;
    xr[1] = e1r + p1r; xi[1] = e1i + p1i;
    xr[5] = e1r - p1r; xi[5] = e1i - p1i;
    xr[2] = e2r + p2r; xi[2] = e2i + p2i;
    xr[6] = e2r - p2r; xi[6] = e2i - p2i;
    xr[3] = e3r + p3r; xi[3] = e3i + p3i;
    xr[7] = e3r - p3r; xi[7] = e3i - p3i;
}

// Tables store (cos th, sin th), th >= 0. Forward multiplies by e^{-i th}.
template <bool INV>
__device__ __forceinline__ void tw_apply(float* xr, float* xi,
                                         const float* c, const float* s)
{
#pragma unroll
    for (int k = 1; k < 8; ++k) {
        float r, i;
        if (!INV) { r = xr[k] * c[k] + xi[k] * s[k]; i = xi[k] * c[k] - xr[k] * s[k]; }
        else      { r = xr[k] * c[k] - xi[k] * s[k]; i = xi[k] * c[k] + xr[k] * s[k]; }
        xr[k] = r; xi[k] = i;
    }
}

__global__ __launch_bounds__(256)
void fv_kernel(const float2* __restrict__ x,
               const float2* __restrict__ pq,    // (P[k], q[k]) k=0..511
               const float2* __restrict__ tw1,   // [(k-1)*64 + t], k=1..7
               const float2* __restrict__ tw8,   // [(k-1)*8 + p],  k=1..7
               float2* __restrict__ out)
{
    __shared__ float sre[4][544], sim[4][544];
    const int tid = threadIdx.x;
    const int r = tid >> 6;      // row within block == wave id
    const int t = tid & 63;      // lane
    float* re = sre[r]; float* im = sim[r];
    const size_t rowbase = ((size_t)blockIdx.x * 4 + r) * 512;  // float2 units

    // twiddle register sets (k=1..7)
    float c1[8], s1[8], c8[8], s8[8];
#pragma unroll
    for (int k = 1; k < 8; ++k) {
        float2 w = tw1[(k - 1) * 64 + t];        c1[k] = w.x; s1[k] = w.y;
        float2 v = tw8[(k - 1) * 8 + (t >> 3)];  c8[k] = v.x; s8[k] = v.y;
    }

    // padded-address bases: pad(e) = e + (e>>4), array stride 544
    const int p0 = (t << 3) + (t >> 1);          // pad(8t); 8t..8t+7 stay consecutive
    const int lt = t + (t >> 4);                 // pad(t + 64k) = lt + 68k
    const int sb = (t & 7) + 68 * (t >> 3);      // pad(S=8 store base)

    float zr[8], zi[8];

    // ---- forward FFT-512 ----
#pragma unroll
    for (int k = 0; k < 8; ++k) {
        float2 v = x[rowbase + t + 64 * k];
        zr[k] = v.x; zi[k] = v.y;
    }
    bfly8<false>(zr, zi);
    tw_apply<false>(zr, zi, c1, s1);
#pragma unroll
    for (int k = 0; k < 8; ++k) { re[p0 + k] = zr[k]; im[p0 + k] = zi[k]; }
#pragma unroll
    for (int k = 0; k < 8; ++k) { zr[k] = re[lt + 68 * k]; zi[k] = im[lt + 68 * k]; }
    bfly8<false>(zr, zi);
    tw_apply<false>(zr, zi, c8, s8);
#pragma unroll
    for (int k = 0; k < 8; ++k) {
        int a = sb + 8 * k + (k >> 1);
        re[a] = zr[k]; im[a] = zi[k];
    }
#pragma unroll
    for (int k = 0; k < 8; ++k) { zr[k] = re[lt + 68 * k]; zi[k] = im[lt + 68 * k]; }
    bfly8<false>(zr, zi);
    // regs now hold Z[t + 64k] in natural order.

    // ---- combine W = P*Z + i*q*conj(Z_mirror), all in regs + shfl ----
    {
        const int src = (64 - t) & 63;
        float vr[8], vi[8];
#pragma unroll
        for (int k = 0; k < 8; ++k) {
            vr[k] = __shfl(zr[7 - k], src, 64);
            vi[k] = __shfl(zi[7 - k], src, 64);
        }
        if (t == 0) {
#pragma unroll
            for (int k = 0; k < 8; ++k) {
                int kk = (8 - k) & 7;
                vr[k] = zr[kk]; vi[k] = zi[kk];
            }
        }
#pragma unroll
        for (int k = 0; k < 8; ++k) {
            float2 g = pq[t + 64 * k];
            float nr = g.x * zr[k] + g.y * vi[k];
            float ni = g.x * zi[k] + g.y * vr[k];
            zr[k] = nr; zi[k] = ni;
        }
    }

    // ---- inverse FFT-512 (input already in stage-1 read layout) ----
    bfly8<true>(zr, zi);
    tw_apply<true>(zr, zi, c1, s1);
#pragma unroll
    for (int k = 0; k < 8; ++k) { re[p0 + k] = zr[k]; im[p0 + k] = zi[k]; }
#pragma unroll
    for (int k = 0; k < 8; ++k) { zr[k] = re[lt + 68 * k]; zi[k] = im[lt + 68 * k]; }
    bfly8<true>(zr, zi);
    tw_apply<true>(zr, zi, c8, s8);
#pragma unroll
    for (int k = 0; k < 8; ++k) {
        int a = sb + 8 * k + (k >> 1);
        re[a] = zr[k]; im[a] = zi[k];
    }
#pragma unroll
    for (int k = 0; k < 8; ++k) { zr[k] = re[lt + 68 * k]; zi[k] = im[lt + 68 * k]; }
    bfly8<true>(zr, zi);
#pragma unroll
    for (int k = 0; k < 8; ++k) {
        out[rowbase + t + 64 * k] = make_float2(zr[k], zi[k]);
    }
}

// Build softmax gate -> (P,q) table and twiddle tables, all in d_ws.
__global__ void gate_kernel(const float* __restrict__ w1,
                            float2* __restrict__ pq,
                            float2* __restrict__ tw1,
                            float2* __restrict__ tw8)
{
    __shared__ float red[1024];
    __shared__ float ex[513];
    const int t = threadIdx.x;  // 1024 threads

    float v = (t < 513) ? w1[t] : -1e30f;
    red[t] = v;
    __syncthreads();
    for (int off = 512; off > 0; off >>= 1) {
        if (t < off) red[t] = fmaxf(red[t], red[t + off]);
        __syncthreads();
    }
    float M = red[0];
    __syncthreads();

    float e = (t < 513) ? expf(w1[t] - M) : 0.0f;
    if (t < 513) ex[t] = e;
    red[t] = e;
    __syncthreads();
    for (int off = 512; off > 0; off >>= 1) {
        if (t < off) red[t] += red[t + off];
        __syncthreads();
    }
    float inv = 1.0f / red[0];
    __syncthreads();

    if (t < 512) {
        float ga = ex[t] * inv;
        float gb = ex[512 - t] * inv;
        float gp = ga + gb, gm = ga - gb;
        float th = (float)t * 6.13592315154256492e-03f;  // pi/512 * t = 2*pi*t/1024
        float sn, cs;
        __sincosf(th, &sn, &cs);
        float P = 0.5f * (gp - gm * sn) * (1.0f / 512.0f);
        float q = 0.5f * (gm * cs) * (1.0f / 512.0f);
        pq[t] = make_float2(P, q);
    }
    if (t < 448) {
        int k = (t >> 6) + 1;
        int j = t & 63;
        float th = (float)(j * k) * 1.22718463151036952e-02f;  // 2*pi/512
        float sn, cs;
        sincosf(th, &sn, &cs);
        tw1[t] = make_float2(cs, sn);
    }
    if (t < 56) {
        int k = (t >> 3) + 1;
        int p = t & 7;
        float th = (float)(p * k) * 9.81747704246810387e-02f;  // 2*pi/64
        float sn, cs;
        sincosf(th, &sn, &cs);
        tw8[t] = make_float2(cs, sn);
    }
}

extern "C" void kernel_launch(void* const* d_in, const int* in_sizes, int n_in,
                              void* d_out, int out_size, void* d_ws, size_t ws_size,
                              hipStream_t stream)
{
    (void)n_in; (void)out_size; (void)ws_size;
    const float2* hidden = (const float2*)d_in[0];   // [32768 rows, 512 float2]
    const float*  w1     = (const float*)d_in[1];    // [513]
    float2* out = (float2*)d_out;

    float2* pq  = (float2*)d_ws;          // 512 float2
    float2* tw1 = pq + 512;               // 448 float2
    float2* tw8 = tw1 + 448;              // 56  float2

    gate_kernel<<<1, 1024, 0, stream>>>(w1, pq, tw1, tw8);

    const int rows   = in_sizes[0] / 1024;   // 32768
    const int blocks = rows / 4;             // 8192
    fv_kernel<<<blocks, 256, 0, stream>>>(hidden, pq, tw1, tw8, out);
}